// Round 1
// baseline (568.810 us; speedup 1.0000x reference)
//
#include <hip/hip_runtime.h>
#include <stdint.h>

#define SEQ 4096
#define HID 2048

typedef __attribute__((ext_vector_type(8))) short short8;
typedef __attribute__((ext_vector_type(4))) float f32x4;
typedef unsigned int u32;

__device__ __forceinline__ short bf16_rne(float f) {
  u32 u = __builtin_bit_cast(u32, f);
  u += 0x7FFFu + ((u >> 16) & 1u);
  return (short)(u >> 16);
}

__device__ __forceinline__ void gload16(const void* gp, void* lp) {
  __builtin_amdgcn_global_load_lds(
      (const __attribute__((address_space(1))) u32*)(uintptr_t)gp,
      (__attribute__((address_space(3))) u32*)(uintptr_t)lp, 16, 0, 0);
}

// ---------------- cast fp32 -> bf16 (8 elems/thread) ----------------
__global__ __launch_bounds__(256) void cast_bf16(const float* __restrict__ in,
                                                 short* __restrict__ out, int n8) {
  int i = blockIdx.x * 256 + threadIdx.x;
  if (i >= n8) return;
  const f32x4* p = (const f32x4*)in + (size_t)i * 2;
  f32x4 a = p[0], b = p[1];
  short8 o;
#pragma unroll
  for (int j = 0; j < 4; ++j) { o[j] = bf16_rne(a[j]); o[j + 4] = bf16_rne(b[j]); }
  *((short8*)out + i) = o;
}

// ---------------- transpose V: vt[c][r] = qkv[r][2560+c] ----------------
__global__ __launch_bounds__(256) void transpose_v(const short* __restrict__ qkv,
                                                   short* __restrict__ vt) {
  __shared__ __align__(16) short tile[64][72];
  int rb = blockIdx.x * 64, cb = blockIdx.y * 64;
  int tid = threadIdx.x;
  int tr = tid >> 3, tc = (tid & 7) * 8;
#pragma unroll
  for (int i = 0; i < 2; ++i)
    *(short8*)&tile[tr + i * 32][tc] =
        *(const short8*)&qkv[(size_t)(rb + tr + i * 32) * 3072 + 2560 + cb + tc];
  __syncthreads();
#pragma unroll
  for (int i = 0; i < 2; ++i) {
    int c = tr + i * 32;
    short8 v;
#pragma unroll
    for (int j = 0; j < 8; ++j) v[j] = tile[tc + j][c];
    *(short8*)&vt[(size_t)(cb + c) * SEQ + rb + tc] = v;
  }
}

// ---------------- GEMM NT: C[m,n] = sum_k A[m,k]*B[n,k] ----------------
// A: M x K bf16, B: N x K bf16 (both row-major), 128x128 tile, BK=32 (m97 structure)
template <typename CT>
__global__ __launch_bounds__(256, 2) void gemm_nt(const short* __restrict__ A,
                                                  const short* __restrict__ B,
                                                  CT* __restrict__ C, int M, int N, int K) {
  __shared__ __align__(16) short As[128 * 32];
  __shared__ __align__(16) short Bs[128 * 32];
  int tid = threadIdx.x, wave = tid >> 6, lane = tid & 63;
  int lr = lane & 15, lg = lane >> 4;
  int wr = wave >> 1, wc = wave & 1;
  size_t rowA0 = (size_t)blockIdx.y * 128, colB0 = (size_t)blockIdx.x * 128;
  f32x4 acc[4][4] = {};

  for (int kt = 0; kt < K; kt += 32) {
#pragma unroll
    for (int c = 0; c < 2; ++c) {
      int chunk = wave * 2 + c;                // 8 chunks of 1KB each (16 rows x 64B)
      int row = chunk * 16 + (lane >> 2);
      int col = (lane & 3) * 8;
      gload16(A + (rowA0 + row) * (size_t)K + kt + col, &As[chunk * 512]);
      gload16(B + (colB0 + row) * (size_t)K + kt + col, &Bs[chunk * 512]);
    }
    __syncthreads();
    short8 a[4], b[4];
#pragma unroll
    for (int i = 0; i < 4; ++i) {
      a[i] = *(const short8*)&As[(wr * 64 + i * 16 + lr) * 32 + lg * 8];
      b[i] = *(const short8*)&Bs[(wc * 64 + i * 16 + lr) * 32 + lg * 8];
    }
#pragma unroll
    for (int i = 0; i < 4; ++i)
#pragma unroll
      for (int j = 0; j < 4; ++j)
        acc[i][j] = __builtin_amdgcn_mfma_f32_16x16x32_bf16(a[i], b[j], acc[i][j], 0, 0, 0);
    __syncthreads();
  }
#pragma unroll
  for (int i = 0; i < 4; ++i)
#pragma unroll
    for (int j = 0; j < 4; ++j)
#pragma unroll
      for (int r = 0; r < 4; ++r) {
        size_t row = rowA0 + wr * 64 + i * 16 + lg * 4 + r;
        size_t col = colB0 + wc * 64 + j * 16 + lr;
        if constexpr (sizeof(CT) == 2) C[row * N + col] = (CT)bf16_rne(acc[i][j][r]);
        else C[row * N + col] = acc[i][j][r];
      }
}

// ---------------- flash attention ----------------
// QKV [4096][3072]: Q at col h*128, K at 2048+kv*128. Vt [512][4096] = V^T.
// Oat [4096][2048] bf16. grid (32 qtiles, 16 heads), 256 thr, wave owns 32 q rows.
__global__ __launch_bounds__(256, 2) void attn_kernel(const short* __restrict__ QKV,
                                                      const short* __restrict__ Vt,
                                                      short* __restrict__ Oat) {
  __shared__ __align__(16) short Ks[32 * 128];   // [t][d], rows XOR-swizzled by (t&7)<<4
  __shared__ __align__(16) short Vs[128 * 32];   // [d][t], rows XOR-swizzled by (d&3)<<4
  __shared__ __align__(16) short Ps[4][32 * 40]; // per-wave P, padded stride 40
  int tid = threadIdx.x, wave = tid >> 6, lane = tid & 63;
  int lr = lane & 15, lg = lane >> 4;
  int h = blockIdx.y, kv = h >> 2;
  int q0 = blockIdx.x * 128 + wave * 32;

  // Q fragments in registers: rows q0..q0+31, d = 0..127
  short8 qf[2][4];
#pragma unroll
  for (int rt = 0; rt < 2; ++rt)
#pragma unroll
    for (int ks = 0; ks < 4; ++ks)
      qf[rt][ks] = *(const short8*)&QKV[(size_t)(q0 + rt * 16 + lr) * 3072 + h * 128 +
                                        ks * 32 + lg * 8];

  f32x4 oacc[2][8] = {};
  float m_run[2][4], l_run[2][4];
#pragma unroll
  for (int rt = 0; rt < 2; ++rt)
#pragma unroll
    for (int r = 0; r < 4; ++r) { m_run[rt][r] = -1e30f; l_run[rt][r] = 0.f; }

  const float sc = 1.44269504089f * 0.08838834764831845f;  // log2e / sqrt(128)
  const short* Kbase = QKV + 2048 + kv * 128;
  const short* Vbase = Vt + (size_t)(kv * 128) * SEQ;

  for (int t0 = 0; t0 < SEQ; t0 += 32) {
    // stage K tile [32][128]: 8 chunks of 1KB (4 rows of 256B each)
#pragma unroll
    for (int c = 0; c < 2; ++c) {
      int chunk = wave * 2 + c;
      int row = chunk * 4 + lg;
      int colb = (lr * 16) ^ ((row & 7) << 4);  // pre-swizzled source byte-in-row
      gload16(Kbase + (size_t)(t0 + row) * 3072 + colb / 2, &Ks[chunk * 512]);
    }
    // stage V^T tile [128][32]: 8 chunks of 1KB (16 rows of 64B each)
#pragma unroll
    for (int c = 0; c < 2; ++c) {
      int chunk = wave * 2 + c;
      int d = chunk * 16 + (lane >> 2);
      int tb = ((lane & 3) * 16) ^ ((d & 3) << 4);
      gload16(Vbase + (size_t)d * SEQ + t0 + tb / 2, &Vs[chunk * 512]);
    }
    __syncthreads();

    // S = Q K^T  (S[q=lg*4+r (+16rt)][t=lr (+16ct)])
    f32x4 sacc[2][2] = {};
#pragma unroll
    for (int ks = 0; ks < 4; ++ks) {
      short8 kf[2];
#pragma unroll
      for (int ct = 0; ct < 2; ++ct) {
        int trow = ct * 16 + lr;
        int cb = (ks * 64 + lg * 16) ^ ((trow & 7) << 4);
        kf[ct] = *(const short8*)&Ks[trow * 128 + cb / 2];
      }
#pragma unroll
      for (int rt = 0; rt < 2; ++rt)
#pragma unroll
        for (int ct = 0; ct < 2; ++ct)
          sacc[rt][ct] =
              __builtin_amdgcn_mfma_f32_16x16x32_bf16(qf[rt][ks], kf[ct], sacc[rt][ct], 0, 0, 0);
    }

    // online softmax over the 32 new columns
#pragma unroll
    for (int rt = 0; rt < 2; ++rt)
#pragma unroll
      for (int r = 0; r < 4; ++r) {
        float mx = fmaxf(sacc[rt][0][r], sacc[rt][1][r]);
        mx = fmaxf(mx, __shfl_xor(mx, 1));
        mx = fmaxf(mx, __shfl_xor(mx, 2));
        mx = fmaxf(mx, __shfl_xor(mx, 4));
        mx = fmaxf(mx, __shfl_xor(mx, 8));
        float mold = m_run[rt][r];
        float mnew = fmaxf(mold, mx);
        float corr = __builtin_amdgcn_exp2f((mold - mnew) * sc);
        float p0 = __builtin_amdgcn_exp2f((sacc[rt][0][r] - mnew) * sc);
        float p1 = __builtin_amdgcn_exp2f((sacc[rt][1][r] - mnew) * sc);
        float rs = p0 + p1;
        rs += __shfl_xor(rs, 1);
        rs += __shfl_xor(rs, 2);
        rs += __shfl_xor(rs, 4);
        rs += __shfl_xor(rs, 8);
        l_run[rt][r] = l_run[rt][r] * corr + rs;
        m_run[rt][r] = mnew;
#pragma unroll
        for (int db = 0; db < 8; ++db) oacc[rt][db][r] *= corr;
        int prow = rt * 16 + lg * 4 + r;
        Ps[wave][prow * 40 + lr] = bf16_rne(p0);
        Ps[wave][prow * 40 + 16 + lr] = bf16_rne(p1);
      }
    __syncthreads();

    // PV: O += P[32q x 32t] * V[32t x 128d]
    short8 pa[2];
#pragma unroll
    for (int rt = 0; rt < 2; ++rt)
      pa[rt] = *(const short8*)&Ps[wave][(rt * 16 + lr) * 40 + lg * 8];
#pragma unroll
    for (int db = 0; db < 8; ++db) {
      int vrow = db * 16 + lr;
      int tb2 = (lg * 16) ^ ((vrow & 3) << 4);
      short8 bv = *(const short8*)&Vs[vrow * 32 + tb2 / 2];
#pragma unroll
      for (int rt = 0; rt < 2; ++rt)
        oacc[rt][db] = __builtin_amdgcn_mfma_f32_16x16x32_bf16(pa[rt], bv, oacc[rt][db], 0, 0, 0);
    }
    __syncthreads();
  }

  // epilogue: divide by l, store bf16
#pragma unroll
  for (int rt = 0; rt < 2; ++rt)
#pragma unroll
    for (int db = 0; db < 8; ++db)
#pragma unroll
      for (int r = 0; r < 4; ++r) {
        size_t row = q0 + rt * 16 + lg * 4 + r;
        size_t col = h * 128 + db * 16 + lr;
        Oat[row * HID + col] = bf16_rne(oacc[rt][db][r] / l_run[rt][r]);
      }
}

extern "C" void kernel_launch(void* const* d_in, const int* in_sizes, int n_in,
                              void* d_out, int out_size, void* d_ws, size_t ws_size,
                              hipStream_t stream) {
  const float* x = (const float*)d_in[0];
  const float* Wq = (const float*)d_in[1];
  const float* Wk = (const float*)d_in[2];
  const float* Wv = (const float*)d_in[3];
  const float* Wo = (const float*)d_in[4];
  float* out = (float*)d_out;
  char* ws = (char*)d_ws;

  // workspace layout (60 MB, with aliasing):
  short* xb = (short*)(ws);                          // [4096][2048]  16MB (later: Oat)
  short* wqkv = (short*)(ws + (16u << 20));          // [3072][2048]  12MB (later: Vt)
  short* wob = (short*)(ws + (28u << 20));           // [2048][2048]   8MB
  short* qkv = (short*)(ws + (36u << 20));           // [4096][3072]  24MB
  short* vt = wqkv;                                  // [512][4096]    4MB
  short* oat = xb;                                   // [4096][2048]  16MB

  cast_bf16<<<4096, 256, 0, stream>>>(x, xb, 1048576);
  cast_bf16<<<2048, 256, 0, stream>>>(Wq, wqkv, 524288);
  cast_bf16<<<512, 256, 0, stream>>>(Wk, wqkv + (size_t)2048 * 2048, 131072);
  cast_bf16<<<512, 256, 0, stream>>>(Wv, wqkv + (size_t)2560 * 2048, 131072);
  cast_bf16<<<2048, 256, 0, stream>>>(Wo, wob, 524288);

  // QKV = x * [Wq;Wk;Wv]^T : [4096][3072]
  gemm_nt<short><<<dim3(24, 32), 256, 0, stream>>>(xb, wqkv, qkv, 4096, 3072, 2048);
  // V^T for the PV step
  transpose_v<<<dim3(64, 8), 256, 0, stream>>>(qkv, vt);
  // fused flash attention -> Oat [4096][2048] bf16
  attn_kernel<<<dim3(32, 16), 256, 0, stream>>>(qkv, vt, oat);
  // out = Oat * Wo^T (fp32 out)
  gemm_nt<float><<<dim3(16, 32), 256, 0, stream>>>(oat, wob, out, 4096, HID, 2048);
}

// Round 2
// 473.777 us; speedup vs baseline: 1.2006x; 1.2006x over previous
//
#include <hip/hip_runtime.h>
#include <stdint.h>

#define SEQ 4096
#define HID 2048

typedef __attribute__((ext_vector_type(8))) short short8;
typedef __attribute__((ext_vector_type(8))) _Float16 half8;
typedef __attribute__((ext_vector_type(4))) float f32x4;
typedef unsigned int u32;

__device__ __forceinline__ short bf16_rne(float f) {
  u32 u = __builtin_bit_cast(u32, f);
  u += 0x7FFFu + ((u >> 16) & 1u);
  return (short)(u >> 16);
}

__device__ __forceinline__ void gload16(const void* gp, void* lp) {
  __builtin_amdgcn_global_load_lds(
      (const __attribute__((address_space(1))) u32*)(uintptr_t)gp,
      (__attribute__((address_space(3))) u32*)(uintptr_t)lp, 16, 0, 0);
}

// ---------------- cast fp32 -> bf16 (8 elems/thread) ----------------
__global__ __launch_bounds__(256) void cast_bf16(const float* __restrict__ in,
                                                 short* __restrict__ out, int n8) {
  int i = blockIdx.x * 256 + threadIdx.x;
  if (i >= n8) return;
  const f32x4* p = (const f32x4*)in + (size_t)i * 2;
  f32x4 a = p[0], b = p[1];
  short8 o;
#pragma unroll
  for (int j = 0; j < 4; ++j) { o[j] = bf16_rne(a[j]); o[j + 4] = bf16_rne(b[j]); }
  *((short8*)out + i) = o;
}

// ---------------- transpose V: vt[c][r] = qkv[r][2560+c] ----------------
__global__ __launch_bounds__(256) void transpose_v(const short* __restrict__ qkv,
                                                   short* __restrict__ vt) {
  __shared__ __align__(16) short tile[64][72];
  int rb = blockIdx.x * 64, cb = blockIdx.y * 64;
  int tid = threadIdx.x;
  int tr = tid >> 3, tc = (tid & 7) * 8;
#pragma unroll
  for (int i = 0; i < 2; ++i)
    *(short8*)&tile[tr + i * 32][tc] =
        *(const short8*)&qkv[(size_t)(rb + tr + i * 32) * 3072 + 2560 + cb + tc];
  __syncthreads();
#pragma unroll
  for (int i = 0; i < 2; ++i) {
    int c = tr + i * 32;
    short8 v;
#pragma unroll
    for (int j = 0; j < 8; ++j) v[j] = tile[tc + j][c];
    *(short8*)&vt[(size_t)(cb + c) * SEQ + rb + tc] = v;
  }
}

// ---------------- GEMM NT: C[m,n] = sum_k A[m,k]*B[n,k] ----------------
template <typename CT>
__global__ __launch_bounds__(256, 2) void gemm_nt(const short* __restrict__ A,
                                                  const short* __restrict__ B,
                                                  CT* __restrict__ C, int M, int N, int K) {
  __shared__ __align__(16) short As[128 * 32];
  __shared__ __align__(16) short Bs[128 * 32];
  int tid = threadIdx.x, wave = tid >> 6, lane = tid & 63;
  int lr = lane & 15, lg = lane >> 4;
  int wr = wave >> 1, wc = wave & 1;
  size_t rowA0 = (size_t)blockIdx.y * 128, colB0 = (size_t)blockIdx.x * 128;
  f32x4 acc[4][4] = {};

  for (int kt = 0; kt < K; kt += 32) {
#pragma unroll
    for (int c = 0; c < 2; ++c) {
      int chunk = wave * 2 + c;
      int row = chunk * 16 + (lane >> 2);
      int col = (lane & 3) * 8;
      gload16(A + (rowA0 + row) * (size_t)K + kt + col, &As[chunk * 512]);
      gload16(B + (colB0 + row) * (size_t)K + kt + col, &Bs[chunk * 512]);
    }
    __syncthreads();
    short8 a[4], b[4];
#pragma unroll
    for (int i = 0; i < 4; ++i) {
      a[i] = *(const short8*)&As[(wr * 64 + i * 16 + lr) * 32 + lg * 8];
      b[i] = *(const short8*)&Bs[(wc * 64 + i * 16 + lr) * 32 + lg * 8];
    }
#pragma unroll
    for (int i = 0; i < 4; ++i)
#pragma unroll
      for (int j = 0; j < 4; ++j)
        acc[i][j] = __builtin_amdgcn_mfma_f32_16x16x32_bf16(a[i], b[j], acc[i][j], 0, 0, 0);
    __syncthreads();
  }
#pragma unroll
  for (int i = 0; i < 4; ++i)
#pragma unroll
    for (int j = 0; j < 4; ++j)
#pragma unroll
      for (int r = 0; r < 4; ++r) {
        size_t row = rowA0 + wr * 64 + i * 16 + lg * 4 + r;
        size_t col = colB0 + wc * 64 + j * 16 + lr;
        if constexpr (sizeof(CT) == 2) C[row * N + col] = (CT)bf16_rne(acc[i][j][r]);
        else C[row * N + col] = acc[i][j][r];
      }
}

// ---------------- flash attention ----------------
// QKV [4096][3072]: Q at col h*128, K at 2048+kv*128. Vt [512][4096] = V^T.
// NSPLIT=1: writes bf16 Oat[4096][2048].
// NSPLIT=2: blockIdx.z = KV partition; writes fp16 unnormalized partial Op + fp32 m/l.
template <int NSPLIT>
__global__ __launch_bounds__(256, 3) void attn_kernel(const short* __restrict__ QKV,
                                                      const short* __restrict__ Vt,
                                                      short* __restrict__ Oat,
                                                      _Float16* __restrict__ Op,
                                                      float* __restrict__ ml) {
  __shared__ __align__(16) short Ks[32 * 128];   // [t][d], rows XOR-swizzled by (t&7)<<4
  __shared__ __align__(16) short Vs[128 * 32];   // [d][t], rows XOR-swizzled by (d&3)<<4
  __shared__ __align__(16) short Ps[4][32 * 40]; // per-wave P, padded stride 40
  int tid = threadIdx.x, wave = tid >> 6, lane = tid & 63;
  int lr = lane & 15, lg = lane >> 4;
  int h = blockIdx.y, kv = h >> 2;
  int part = (NSPLIT == 2) ? blockIdx.z : 0;
  int q0 = blockIdx.x * 128 + wave * 32;

  short8 qf[2][4];
#pragma unroll
  for (int rt = 0; rt < 2; ++rt)
#pragma unroll
    for (int ks = 0; ks < 4; ++ks)
      qf[rt][ks] = *(const short8*)&QKV[(size_t)(q0 + rt * 16 + lr) * 3072 + h * 128 +
                                        ks * 32 + lg * 8];

  f32x4 oacc[2][8] = {};
  float m_run[2][4], lsum[2][4];
#pragma unroll
  for (int rt = 0; rt < 2; ++rt)
#pragma unroll
    for (int r = 0; r < 4; ++r) { m_run[rt][r] = -1e30f; lsum[rt][r] = 0.f; }

  const float sc = 1.44269504089f * 0.08838834764831845f;  // log2e / sqrt(128)
  const float THR_S = 60.f;                                 // defer-max threshold (S units)
  const short* Kbase = QKV + 2048 + kv * 128;
  const short* Vbase = Vt + (size_t)(kv * 128) * SEQ;

  const int tbeg = part * (SEQ / NSPLIT);
  const int tend = tbeg + SEQ / NSPLIT;
  for (int t0 = tbeg; t0 < tend; t0 += 32) {
#pragma unroll
    for (int c = 0; c < 2; ++c) {
      int chunk = wave * 2 + c;
      int row = chunk * 4 + lg;
      int colb = (lr * 16) ^ ((row & 7) << 4);
      gload16(Kbase + (size_t)(t0 + row) * 3072 + colb / 2, &Ks[chunk * 512]);
    }
#pragma unroll
    for (int c = 0; c < 2; ++c) {
      int chunk = wave * 2 + c;
      int d = chunk * 16 + (lane >> 2);
      int tb = ((lane & 3) * 16) ^ ((d & 3) << 4);
      gload16(Vbase + (size_t)d * SEQ + t0 + tb / 2, &Vs[chunk * 512]);
    }
    __syncthreads();

    // S = Q K^T
    f32x4 sacc[2][2] = {};
    __builtin_amdgcn_s_setprio(1);
#pragma unroll
    for (int ks = 0; ks < 4; ++ks) {
      short8 kf[2];
#pragma unroll
      for (int ct = 0; ct < 2; ++ct) {
        int trow = ct * 16 + lr;
        int cb = (ks * 64 + lg * 16) ^ ((trow & 7) << 4);
        kf[ct] = *(const short8*)&Ks[trow * 128 + cb / 2];
      }
#pragma unroll
      for (int rt = 0; rt < 2; ++rt)
#pragma unroll
        for (int ct = 0; ct < 2; ++ct)
          sacc[rt][ct] =
              __builtin_amdgcn_mfma_f32_16x16x32_bf16(qf[rt][ks], kf[ct], sacc[rt][ct], 0, 0, 0);
    }
    __builtin_amdgcn_s_setprio(0);

    // online softmax: tile max (4 shuffles/row), defer-max rescale, per-lane partial l
    float mx[2][4];
    int need = 0;
#pragma unroll
    for (int rt = 0; rt < 2; ++rt)
#pragma unroll
      for (int r = 0; r < 4; ++r) {
        float v = fmaxf(sacc[rt][0][r], sacc[rt][1][r]);
        v = fmaxf(v, __shfl_xor(v, 1));
        v = fmaxf(v, __shfl_xor(v, 2));
        v = fmaxf(v, __shfl_xor(v, 4));
        v = fmaxf(v, __shfl_xor(v, 8));
        mx[rt][r] = v;
        need |= (v > m_run[rt][r] + THR_S) ? 1 : 0;
      }
    if (__any(need)) {
#pragma unroll
      for (int rt = 0; rt < 2; ++rt)
#pragma unroll
        for (int r = 0; r < 4; ++r) {
          float mnew = fmaxf(m_run[rt][r], mx[rt][r]);
          float corr = __builtin_amdgcn_exp2f((m_run[rt][r] - mnew) * sc);
          lsum[rt][r] *= corr;
          m_run[rt][r] = mnew;
#pragma unroll
          for (int db = 0; db < 8; ++db) oacc[rt][db][r] *= corr;
        }
    }
#pragma unroll
    for (int rt = 0; rt < 2; ++rt)
#pragma unroll
      for (int r = 0; r < 4; ++r) {
        float p0 = __builtin_amdgcn_exp2f((sacc[rt][0][r] - m_run[rt][r]) * sc);
        float p1 = __builtin_amdgcn_exp2f((sacc[rt][1][r] - m_run[rt][r]) * sc);
        lsum[rt][r] += p0 + p1;
        int prow = rt * 16 + lg * 4 + r;
        Ps[wave][prow * 40 + lr] = bf16_rne(p0);
        Ps[wave][prow * 40 + 16 + lr] = bf16_rne(p1);
      }
    __syncthreads();

    // PV: O += P[32q x 32t] * V[32t x 128d]
    short8 pa[2];
#pragma unroll
    for (int rt = 0; rt < 2; ++rt)
      pa[rt] = *(const short8*)&Ps[wave][(rt * 16 + lr) * 40 + lg * 8];
    __builtin_amdgcn_s_setprio(1);
#pragma unroll
    for (int db = 0; db < 8; ++db) {
      int vrow = db * 16 + lr;
      int tb2 = (lg * 16) ^ ((vrow & 3) << 4);
      short8 bv = *(const short8*)&Vs[vrow * 32 + tb2 / 2];
#pragma unroll
      for (int rt = 0; rt < 2; ++rt)
        oacc[rt][db] = __builtin_amdgcn_mfma_f32_16x16x32_bf16(pa[rt], bv, oacc[rt][db], 0, 0, 0);
    }
    __builtin_amdgcn_s_setprio(0);
    __syncthreads();
  }

  // final cross-lane reduce of per-lane partial l
#pragma unroll
  for (int rt = 0; rt < 2; ++rt)
#pragma unroll
    for (int r = 0; r < 4; ++r) {
      float s = lsum[rt][r];
      s += __shfl_xor(s, 1);
      s += __shfl_xor(s, 2);
      s += __shfl_xor(s, 4);
      s += __shfl_xor(s, 8);
      lsum[rt][r] = s;
    }

  if constexpr (NSPLIT == 1) {
#pragma unroll
    for (int rt = 0; rt < 2; ++rt)
#pragma unroll
      for (int db = 0; db < 8; ++db)
#pragma unroll
        for (int r = 0; r < 4; ++r) {
          size_t row = q0 + rt * 16 + lg * 4 + r;
          size_t col = h * 128 + db * 16 + lr;
          Oat[row * HID + col] = bf16_rne(oacc[rt][db][r] / lsum[rt][r]);
        }
  } else {
    _Float16* Obase = Op + (size_t)part * SEQ * HID;
#pragma unroll
    for (int rt = 0; rt < 2; ++rt)
#pragma unroll
      for (int db = 0; db < 8; ++db)
#pragma unroll
        for (int r = 0; r < 4; ++r) {
          size_t row = q0 + rt * 16 + lg * 4 + r;
          size_t col = h * 128 + db * 16 + lr;
          Obase[row * HID + col] = (_Float16)oacc[rt][db][r];
        }
    if (lr == 0) {
#pragma unroll
      for (int rt = 0; rt < 2; ++rt)
#pragma unroll
        for (int r = 0; r < 4; ++r) {
          size_t row = q0 + rt * 16 + lg * 4 + r;
          size_t base = (((size_t)part * SEQ + row) * 16 + h) * 2;
          ml[base] = m_run[rt][r];
          ml[base + 1] = lsum[rt][r];
        }
    }
  }
}

// ---------------- merge two KV partitions ----------------
__global__ __launch_bounds__(256) void merge_parts(const _Float16* __restrict__ Op,
                                                   const float* __restrict__ ml,
                                                   short* __restrict__ Oat) {
  const float sc = 1.44269504089f * 0.08838834764831845f;
  int i = blockIdx.x * 256 + threadIdx.x;   // 1M threads, 8 cols each
  int row = i >> 8;
  int col = (i & 255) * 8;
  int h = col >> 7;
  const float* a = ml + (((size_t)row) * 16 + h) * 2;
  const float* b = ml + (((size_t)SEQ + row) * 16 + h) * 2;
  float m1 = a[0], l1 = a[1], m2 = b[0], l2 = b[1];
  float M = fmaxf(m1, m2);
  float e1 = __builtin_amdgcn_exp2f((m1 - M) * sc);
  float e2 = __builtin_amdgcn_exp2f((m2 - M) * sc);
  float inv = 1.f / (l1 * e1 + l2 * e2);
  half8 o1 = *(const half8*)&Op[(size_t)row * HID + col];
  half8 o2 = *(const half8*)&Op[(size_t)SEQ * HID + (size_t)row * HID + col];
  short8 o;
#pragma unroll
  for (int j = 0; j < 8; ++j)
    o[j] = bf16_rne(((float)o1[j] * e1 + (float)o2[j] * e2) * inv);
  *(short8*)&Oat[(size_t)row * HID + col] = o;
}

extern "C" void kernel_launch(void* const* d_in, const int* in_sizes, int n_in,
                              void* d_out, int out_size, void* d_ws, size_t ws_size,
                              hipStream_t stream) {
  const float* x = (const float*)d_in[0];
  const float* Wq = (const float*)d_in[1];
  const float* Wk = (const float*)d_in[2];
  const float* Wv = (const float*)d_in[3];
  const float* Wo = (const float*)d_in[4];
  float* out = (float*)d_out;
  char* ws = (char*)d_ws;

  // workspace layout:
  short* xb = (short*)(ws);                          // [4096][2048]  16MB (later: Oat)
  short* wqkv = (short*)(ws + (16u << 20));          // [3072][2048]  12MB (later: Vt)
  short* wob = (short*)(ws + (28u << 20));           // [2048][2048]   8MB
  short* qkv = (short*)(ws + (36u << 20));           // [4096][3072]  24MB
  short* vt = wqkv;                                  // [512][4096]    4MB
  short* oat = xb;                                   // [4096][2048]  16MB
  // KV-split partials (only if workspace permits): 32MB fp16 + 1MB fp32
  _Float16* opart = (_Float16*)(ws + 62914560u);
  float* mlb = (float*)(ws + 62914560u + 33554432u);
  const bool split = ws_size >= (size_t)(62914560u + 33554432u + 1048576u);

  cast_bf16<<<4096, 256, 0, stream>>>(x, xb, 1048576);
  cast_bf16<<<2048, 256, 0, stream>>>(Wq, wqkv, 524288);
  cast_bf16<<<512, 256, 0, stream>>>(Wk, wqkv + (size_t)2048 * 2048, 131072);
  cast_bf16<<<512, 256, 0, stream>>>(Wv, wqkv + (size_t)2560 * 2048, 131072);
  cast_bf16<<<2048, 256, 0, stream>>>(Wo, wob, 524288);

  // QKV = x * [Wq;Wk;Wv]^T : [4096][3072]
  gemm_nt<short><<<dim3(24, 32), 256, 0, stream>>>(xb, wqkv, qkv, 4096, 3072, 2048);
  // V^T for the PV step
  transpose_v<<<dim3(64, 8), 256, 0, stream>>>(qkv, vt);
  // fused flash attention
  if (split) {
    attn_kernel<2><<<dim3(32, 16, 2), 256, 0, stream>>>(qkv, vt, nullptr, opart, mlb);
    merge_parts<<<4096, 256, 0, stream>>>(opart, mlb, oat);
  } else {
    attn_kernel<1><<<dim3(32, 16, 1), 256, 0, stream>>>(qkv, vt, oat, nullptr, nullptr);
  }
  // out = Oat * Wo^T (fp32 out)
  gemm_nt<float><<<dim3(16, 32), 256, 0, stream>>>(oat, wob, out, 4096, HID, 2048);
}

// Round 3
// 418.804 us; speedup vs baseline: 1.3582x; 1.1313x over previous
//
#include <hip/hip_runtime.h>
#include <stdint.h>

#define SEQ 4096
#define HID 2048

typedef __attribute__((ext_vector_type(8))) short short8;
typedef __attribute__((ext_vector_type(8))) _Float16 half8;
typedef __attribute__((ext_vector_type(4))) float f32x4;
typedef unsigned int u32;

__device__ __forceinline__ short bf16_rne(float f) {
  u32 u = __builtin_bit_cast(u32, f);
  u += 0x7FFFu + ((u >> 16) & 1u);
  return (short)(u >> 16);
}

__device__ __forceinline__ void gload16(const void* gp, void* lp) {
  __builtin_amdgcn_global_load_lds(
      (const __attribute__((address_space(1))) u32*)(uintptr_t)gp,
      (__attribute__((address_space(3))) u32*)(uintptr_t)lp, 16, 0, 0);
}

// ---------------- cast fp32 -> bf16 (8 elems/thread) ----------------
__global__ __launch_bounds__(256) void cast_bf16(const float* __restrict__ in,
                                                 short* __restrict__ out, int n8) {
  int i = blockIdx.x * 256 + threadIdx.x;
  if (i >= n8) return;
  const f32x4* p = (const f32x4*)in + (size_t)i * 2;
  f32x4 a = p[0], b = p[1];
  short8 o;
#pragma unroll
  for (int j = 0; j < 4; ++j) { o[j] = bf16_rne(a[j]); o[j + 4] = bf16_rne(b[j]); }
  *((short8*)out + i) = o;
}

// ---------------- transpose V: vt[c][r] = qkv[r][2560+c] ----------------
__global__ __launch_bounds__(256) void transpose_v(const short* __restrict__ qkv,
                                                   short* __restrict__ vt) {
  __shared__ __align__(16) short tile[64][72];
  int rb = blockIdx.x * 64, cb = blockIdx.y * 64;
  int tid = threadIdx.x;
  int tr = tid >> 3, tc = (tid & 7) * 8;
#pragma unroll
  for (int i = 0; i < 2; ++i)
    *(short8*)&tile[tr + i * 32][tc] =
        *(const short8*)&qkv[(size_t)(rb + tr + i * 32) * 3072 + 2560 + cb + tc];
  __syncthreads();
#pragma unroll
  for (int i = 0; i < 2; ++i) {
    int c = tr + i * 32;
    short8 v;
#pragma unroll
    for (int j = 0; j < 8; ++j) v[j] = tile[tc + j][c];
    *(short8*)&vt[(size_t)(cb + c) * SEQ + rb + tc] = v;
  }
}

// ---------------- GEMM NT: C[m,n] = sum_k A[m,k]*B[n,k] ----------------
template <typename CT>
__global__ __launch_bounds__(256, 2) void gemm_nt(const short* __restrict__ A,
                                                  const short* __restrict__ B,
                                                  CT* __restrict__ C, int M, int N, int K) {
  __shared__ __align__(16) short As[128 * 32];
  __shared__ __align__(16) short Bs[128 * 32];
  int tid = threadIdx.x, wave = tid >> 6, lane = tid & 63;
  int lr = lane & 15, lg = lane >> 4;
  int wr = wave >> 1, wc = wave & 1;
  size_t rowA0 = (size_t)blockIdx.y * 128, colB0 = (size_t)blockIdx.x * 128;
  f32x4 acc[4][4] = {};

  for (int kt = 0; kt < K; kt += 32) {
#pragma unroll
    for (int c = 0; c < 2; ++c) {
      int chunk = wave * 2 + c;
      int row = chunk * 16 + (lane >> 2);
      int col = (lane & 3) * 8;
      gload16(A + (rowA0 + row) * (size_t)K + kt + col, &As[chunk * 512]);
      gload16(B + (colB0 + row) * (size_t)K + kt + col, &Bs[chunk * 512]);
    }
    __syncthreads();
    short8 a[4], b[4];
#pragma unroll
    for (int i = 0; i < 4; ++i) {
      a[i] = *(const short8*)&As[(wr * 64 + i * 16 + lr) * 32 + lg * 8];
      b[i] = *(const short8*)&Bs[(wc * 64 + i * 16 + lr) * 32 + lg * 8];
    }
#pragma unroll
    for (int i = 0; i < 4; ++i)
#pragma unroll
      for (int j = 0; j < 4; ++j)
        acc[i][j] = __builtin_amdgcn_mfma_f32_16x16x32_bf16(a[i], b[j], acc[i][j], 0, 0, 0);
    __syncthreads();
  }
#pragma unroll
  for (int i = 0; i < 4; ++i)
#pragma unroll
    for (int j = 0; j < 4; ++j)
#pragma unroll
      for (int r = 0; r < 4; ++r) {
        size_t row = rowA0 + wr * 64 + i * 16 + lg * 4 + r;
        size_t col = colB0 + wc * 64 + j * 16 + lr;
        if constexpr (sizeof(CT) == 2) C[row * N + col] = (CT)bf16_rne(acc[i][j][r]);
        else C[row * N + col] = acc[i][j][r];
      }
}

// ---------------- flash attention (double-buffered, 1 barrier/iter) ----------------
// QKV [4096][3072]: Q at col h*128, K at 2048+kv*128. Vt [512][4096] = V^T.
// K LDS: [32 t][128 d], 256B rows, byte XOR (t&7)<<4.
// V LDS: [32 r][128], row r holds d=4r..4r+3 (64B each), byte XOR (r&7)<<4.
template <int NSPLIT>
__global__ __launch_bounds__(256, 2) void attn_kernel(const short* __restrict__ QKV,
                                                      const short* __restrict__ Vt,
                                                      short* __restrict__ Oat,
                                                      _Float16* __restrict__ Op,
                                                      float* __restrict__ ml) {
  __shared__ __align__(16) short Ks[2][32 * 128];
  __shared__ __align__(16) short Vs[2][32 * 128];
  __shared__ __align__(16) short Ps[4][32 * 40];  // per-wave P, padded stride 40
  int tid = threadIdx.x, wave = tid >> 6, lane = tid & 63;
  int lr = lane & 15, lg = lane >> 4;
  int h = blockIdx.y, kv = h >> 2;
  int part = (NSPLIT == 2) ? blockIdx.z : 0;
  int q0 = blockIdx.x * 128 + wave * 32;

  short8 qf[2][4];
#pragma unroll
  for (int rt = 0; rt < 2; ++rt)
#pragma unroll
    for (int ks = 0; ks < 4; ++ks)
      qf[rt][ks] = *(const short8*)&QKV[(size_t)(q0 + rt * 16 + lr) * 3072 + h * 128 +
                                        ks * 32 + lg * 8];

  f32x4 oacc[2][8] = {};
  float m_run[2][4], lsum[2][4];
#pragma unroll
  for (int rt = 0; rt < 2; ++rt)
#pragma unroll
    for (int r = 0; r < 4; ++r) { m_run[rt][r] = -1e30f; lsum[rt][r] = 0.f; }

  const float sc = 1.44269504089f * 0.08838834764831845f;  // log2e / sqrt(128)
  const float THR_S = 60.f;                                 // defer-max threshold (S units)
  const short* Kbase = QKV + 2048 + kv * 128;
  const short* Vbase = Vt + (size_t)(kv * 128) * SEQ;

  auto stageK = [&](int b, int t0) {
#pragma unroll
    for (int c = 0; c < 2; ++c) {
      int chunk = wave * 2 + c;
      int row = chunk * 4 + lg;
      int colb = (lr * 16) ^ ((row & 7) << 4);
      gload16(Kbase + (size_t)(t0 + row) * 3072 + colb / 2, &Ks[b][chunk * 512]);
    }
  };
  auto stageV = [&](int b, int t0) {
#pragma unroll
    for (int c = 0; c < 2; ++c) {
      int chunk = wave * 2 + c;
      int r = chunk * 4 + lg;
      int lb = (lr * 16) ^ ((r & 7) << 4);
      int d = r * 4 + (lb >> 6);
      gload16(Vbase + (size_t)d * SEQ + t0 + ((lb & 63) >> 1), &Vs[b][chunk * 512]);
    }
  };

  const int tbeg = part * (SEQ / NSPLIT);
  const int tend = tbeg + SEQ / NSPLIT;

  stageK(0, tbeg);
  stageV(0, tbeg);
  __syncthreads();
  int buf = 0;

  for (int t0 = tbeg; t0 < tend; t0 += 32) {
    int tn = (t0 + 32 < tend) ? t0 + 32 : tbeg;  // clamped: last iter reloads harmlessly
    stageK(buf ^ 1, tn);
    stageV(buf ^ 1, tn);

    // S = Q K^T from Ks[buf]
    f32x4 sacc[2][2] = {};
    __builtin_amdgcn_s_setprio(1);
#pragma unroll
    for (int ks = 0; ks < 4; ++ks) {
      short8 kf[2];
#pragma unroll
      for (int ct = 0; ct < 2; ++ct) {
        int trow = ct * 16 + lr;
        int cb = (ks * 64 + lg * 16) ^ ((trow & 7) << 4);
        kf[ct] = *(const short8*)&Ks[buf][trow * 128 + cb / 2];
      }
#pragma unroll
      for (int rt = 0; rt < 2; ++rt)
#pragma unroll
        for (int ct = 0; ct < 2; ++ct)
          sacc[rt][ct] =
              __builtin_amdgcn_mfma_f32_16x16x32_bf16(qf[rt][ks], kf[ct], sacc[rt][ct], 0, 0, 0);
    }
    __builtin_amdgcn_s_setprio(0);

    // online softmax: tile max (4 shuffles/row), defer-max rescale, per-lane partial l
    float mx[2][4];
    int need = 0;
#pragma unroll
    for (int rt = 0; rt < 2; ++rt)
#pragma unroll
      for (int r = 0; r < 4; ++r) {
        float v = fmaxf(sacc[rt][0][r], sacc[rt][1][r]);
        v = fmaxf(v, __shfl_xor(v, 1));
        v = fmaxf(v, __shfl_xor(v, 2));
        v = fmaxf(v, __shfl_xor(v, 4));
        v = fmaxf(v, __shfl_xor(v, 8));
        mx[rt][r] = v;
        need |= (v > m_run[rt][r] + THR_S) ? 1 : 0;
      }
    if (__any(need)) {
#pragma unroll
      for (int rt = 0; rt < 2; ++rt)
#pragma unroll
        for (int r = 0; r < 4; ++r) {
          float mnew = fmaxf(m_run[rt][r], mx[rt][r]);
          float corr = __builtin_amdgcn_exp2f((m_run[rt][r] - mnew) * sc);
          lsum[rt][r] *= corr;
          m_run[rt][r] = mnew;
#pragma unroll
          for (int db = 0; db < 8; ++db) oacc[rt][db][r] *= corr;
        }
    }
#pragma unroll
    for (int rt = 0; rt < 2; ++rt)
#pragma unroll
      for (int r = 0; r < 4; ++r) {
        float p0 = __builtin_amdgcn_exp2f((sacc[rt][0][r] - m_run[rt][r]) * sc);
        float p1 = __builtin_amdgcn_exp2f((sacc[rt][1][r] - m_run[rt][r]) * sc);
        lsum[rt][r] += p0 + p1;
        int prow = rt * 16 + lg * 4 + r;
        Ps[wave][prow * 40 + lr] = bf16_rne(p0);
        Ps[wave][prow * 40 + 16 + lr] = bf16_rne(p1);
      }
    // Ps is wave-private: no barrier needed, compiler orders via lgkmcnt.

    // PV: O += P[32q x 32t] * V[32t x 128d] from Vs[buf]
    short8 pa[2];
#pragma unroll
    for (int rt = 0; rt < 2; ++rt)
      pa[rt] = *(const short8*)&Ps[wave][(rt * 16 + lr) * 40 + lg * 8];
    __builtin_amdgcn_s_setprio(1);
#pragma unroll
    for (int db = 0; db < 8; ++db) {
      int d = db * 16 + lr;
      int r = d >> 2;
      int lb = ((d & 3) * 64 + lg * 16) ^ ((r & 7) << 4);
      short8 bv = *(const short8*)&Vs[buf][r * 128 + lb / 2];
#pragma unroll
      for (int rt = 0; rt < 2; ++rt)
        oacc[rt][db] = __builtin_amdgcn_mfma_f32_16x16x32_bf16(pa[rt], bv, oacc[rt][db], 0, 0, 0);
    }
    __builtin_amdgcn_s_setprio(0);

    __syncthreads();  // drains vmcnt(0): next buffer staged; all waves done reading buf
    buf ^= 1;
  }

  // final cross-lane reduce of per-lane partial l
#pragma unroll
  for (int rt = 0; rt < 2; ++rt)
#pragma unroll
    for (int r = 0; r < 4; ++r) {
      float s = lsum[rt][r];
      s += __shfl_xor(s, 1);
      s += __shfl_xor(s, 2);
      s += __shfl_xor(s, 4);
      s += __shfl_xor(s, 8);
      lsum[rt][r] = s;
    }

  if constexpr (NSPLIT == 1) {
#pragma unroll
    for (int rt = 0; rt < 2; ++rt)
#pragma unroll
      for (int db = 0; db < 8; ++db)
#pragma unroll
        for (int r = 0; r < 4; ++r) {
          size_t row = q0 + rt * 16 + lg * 4 + r;
          size_t col = h * 128 + db * 16 + lr;
          Oat[row * HID + col] = bf16_rne(oacc[rt][db][r] / lsum[rt][r]);
        }
  } else {
    _Float16* Obase = Op + (size_t)part * SEQ * HID;
#pragma unroll
    for (int rt = 0; rt < 2; ++rt)
#pragma unroll
      for (int db = 0; db < 8; ++db)
#pragma unroll
        for (int r = 0; r < 4; ++r) {
          size_t row = q0 + rt * 16 + lg * 4 + r;
          size_t col = h * 128 + db * 16 + lr;
          Obase[row * HID + col] = (_Float16)oacc[rt][db][r];
        }
    if (lr == 0) {
#pragma unroll
      for (int rt = 0; rt < 2; ++rt)
#pragma unroll
        for (int r = 0; r < 4; ++r) {
          size_t row = q0 + rt * 16 + lg * 4 + r;
          size_t base = (((size_t)part * SEQ + row) * 16 + h) * 2;
          ml[base] = m_run[rt][r];
          ml[base + 1] = lsum[rt][r];
        }
    }
  }
}

// ---------------- merge two KV partitions ----------------
__global__ __launch_bounds__(256) void merge_parts(const _Float16* __restrict__ Op,
                                                   const float* __restrict__ ml,
                                                   short* __restrict__ Oat) {
  const float sc = 1.44269504089f * 0.08838834764831845f;
  int i = blockIdx.x * 256 + threadIdx.x;
  int row = i >> 8;
  int col = (i & 255) * 8;
  int h = col >> 7;
  const float* a = ml + (((size_t)row) * 16 + h) * 2;
  const float* b = ml + (((size_t)SEQ + row) * 16 + h) * 2;
  float m1 = a[0], l1 = a[1], m2 = b[0], l2 = b[1];
  float M = fmaxf(m1, m2);
  float e1 = __builtin_amdgcn_exp2f((m1 - M) * sc);
  float e2 = __builtin_amdgcn_exp2f((m2 - M) * sc);
  float inv = 1.f / (l1 * e1 + l2 * e2);
  half8 o1 = *(const half8*)&Op[(size_t)row * HID + col];
  half8 o2 = *(const half8*)&Op[(size_t)SEQ * HID + (size_t)row * HID + col];
  short8 o;
#pragma unroll
  for (int j = 0; j < 8; ++j)
    o[j] = bf16_rne(((float)o1[j] * e1 + (float)o2[j] * e2) * inv);
  *(short8*)&Oat[(size_t)row * HID + col] = o;
}

extern "C" void kernel_launch(void* const* d_in, const int* in_sizes, int n_in,
                              void* d_out, int out_size, void* d_ws, size_t ws_size,
                              hipStream_t stream) {
  const float* x = (const float*)d_in[0];
  const float* Wq = (const float*)d_in[1];
  const float* Wk = (const float*)d_in[2];
  const float* Wv = (const float*)d_in[3];
  const float* Wo = (const float*)d_in[4];
  float* out = (float*)d_out;
  char* ws = (char*)d_ws;

  // workspace layout:
  short* xb = (short*)(ws);                          // [4096][2048]  16MB (later: Oat)
  short* wqkv = (short*)(ws + (16u << 20));          // [3072][2048]  12MB (later: Vt)
  short* wob = (short*)(ws + (28u << 20));           // [2048][2048]   8MB
  short* qkv = (short*)(ws + (36u << 20));           // [4096][3072]  24MB
  short* vt = wqkv;                                  // [512][4096]    4MB
  short* oat = xb;                                   // [4096][2048]  16MB
  _Float16* opart = (_Float16*)(ws + 62914560u);     // [2][4096][2048] fp16 32MB
  float* mlb = (float*)(ws + 62914560u + 33554432u); // [2][4096][16][2] 1MB
  const bool split = ws_size >= (size_t)(62914560u + 33554432u + 1048576u);

  cast_bf16<<<4096, 256, 0, stream>>>(x, xb, 1048576);
  cast_bf16<<<2048, 256, 0, stream>>>(Wq, wqkv, 524288);
  cast_bf16<<<512, 256, 0, stream>>>(Wk, wqkv + (size_t)2048 * 2048, 131072);
  cast_bf16<<<512, 256, 0, stream>>>(Wv, wqkv + (size_t)2560 * 2048, 131072);
  cast_bf16<<<2048, 256, 0, stream>>>(Wo, wob, 524288);

  // QKV = x * [Wq;Wk;Wv]^T : [4096][3072]
  gemm_nt<short><<<dim3(24, 32), 256, 0, stream>>>(xb, wqkv, qkv, 4096, 3072, 2048);
  // V^T for the PV step
  transpose_v<<<dim3(64, 8), 256, 0, stream>>>(qkv, vt);
  // fused flash attention
  if (split) {
    attn_kernel<2><<<dim3(32, 16, 2), 256, 0, stream>>>(qkv, vt, nullptr, opart, mlb);
    merge_parts<<<4096, 256, 0, stream>>>(opart, mlb, oat);
  } else {
    attn_kernel<1><<<dim3(32, 16, 1), 256, 0, stream>>>(qkv, vt, oat, nullptr, nullptr);
  }
  // out = Oat * Wo^T (fp32 out)
  gemm_nt<float><<<dim3(16, 32), 256, 0, stream>>>(oat, wob, out, 4096, HID, 2048);
}

// Round 4
// 392.012 us; speedup vs baseline: 1.4510x; 1.0683x over previous
//
#include <hip/hip_runtime.h>
#include <stdint.h>

#define SEQ 4096
#define HID 2048

typedef __attribute__((ext_vector_type(8))) short short8;
typedef __attribute__((ext_vector_type(8))) _Float16 half8;
typedef __attribute__((ext_vector_type(4))) float f32x4;
typedef unsigned int u32;

__device__ __forceinline__ short bf16_rne(float f) {
  u32 u = __builtin_bit_cast(u32, f);
  u += 0x7FFFu + ((u >> 16) & 1u);
  return (short)(u >> 16);
}

__device__ __forceinline__ void gload16(const void* gp, void* lp) {
  __builtin_amdgcn_global_load_lds(
      (const __attribute__((address_space(1))) u32*)(uintptr_t)gp,
      (__attribute__((address_space(3))) u32*)(uintptr_t)lp, 16, 0, 0);
}

// ---------------- cast fp32 -> bf16 (8 elems/thread) ----------------
__global__ __launch_bounds__(256) void cast_bf16(const float* __restrict__ in,
                                                 short* __restrict__ out, int n8) {
  int i = blockIdx.x * 256 + threadIdx.x;
  if (i >= n8) return;
  const f32x4* p = (const f32x4*)in + (size_t)i * 2;
  f32x4 a = p[0], b = p[1];
  short8 o;
#pragma unroll
  for (int j = 0; j < 4; ++j) { o[j] = bf16_rne(a[j]); o[j + 4] = bf16_rne(b[j]); }
  *((short8*)out + i) = o;
}

// ---------------- transpose V with per-32-chunk t-interleave ----------------
// vt[d][chunkbase + c] = V[t = chunkbase + (c>>1) + (c&1)*16][d]
// (t-order interleaved so attn can ds_write_b32 packed P pairs (t, t+16))
__global__ __launch_bounds__(256) void transpose_v(const short* __restrict__ qkv,
                                                   short* __restrict__ vt) {
  __shared__ __align__(16) short tile[64][72];
  int rb = blockIdx.x * 64, cb = blockIdx.y * 64;
  int tid = threadIdx.x;
  int tr = tid >> 3, tc = (tid & 7) * 8;
#pragma unroll
  for (int i = 0; i < 2; ++i)
    *(short8*)&tile[tr + i * 32][tc] =
        *(const short8*)&qkv[(size_t)(rb + tr + i * 32) * 3072 + 2560 + cb + tc];
  __syncthreads();
#pragma unroll
  for (int i = 0; i < 2; ++i) {
    int c = tr + i * 32;
    short8 v;
#pragma unroll
    for (int j = 0; j < 8; ++j) {
      int pos = tc + j;                          // output position in 64-t block
      int p = pos & 31, ch = pos >> 5;
      int tl = ch * 32 + (p >> 1) + (p & 1) * 16;  // source t-local
      v[j] = tile[tl][c];
    }
    *(short8*)&vt[(size_t)(cb + c) * SEQ + rb + tc] = v;
  }
}

// ---------------- GEMM NT: C[m,n] = sum_k A[m,k]*B[n,k] ----------------
template <typename CT>
__global__ __launch_bounds__(256, 2) void gemm_nt(const short* __restrict__ A,
                                                  const short* __restrict__ B,
                                                  CT* __restrict__ C, int M, int N, int K) {
  __shared__ __align__(16) short As[128 * 32];
  __shared__ __align__(16) short Bs[128 * 32];
  int tid = threadIdx.x, wave = tid >> 6, lane = tid & 63;
  int lr = lane & 15, lg = lane >> 4;
  int wr = wave >> 1, wc = wave & 1;
  size_t rowA0 = (size_t)blockIdx.y * 128, colB0 = (size_t)blockIdx.x * 128;
  f32x4 acc[4][4] = {};

  for (int kt = 0; kt < K; kt += 32) {
#pragma unroll
    for (int c = 0; c < 2; ++c) {
      int chunk = wave * 2 + c;
      int row = chunk * 16 + (lane >> 2);
      int col = (lane & 3) * 8;
      gload16(A + (rowA0 + row) * (size_t)K + kt + col, &As[chunk * 512]);
      gload16(B + (colB0 + row) * (size_t)K + kt + col, &Bs[chunk * 512]);
    }
    __syncthreads();
    short8 a[4], b[4];
#pragma unroll
    for (int i = 0; i < 4; ++i) {
      a[i] = *(const short8*)&As[(wr * 64 + i * 16 + lr) * 32 + lg * 8];
      b[i] = *(const short8*)&Bs[(wc * 64 + i * 16 + lr) * 32 + lg * 8];
    }
#pragma unroll
    for (int i = 0; i < 4; ++i)
#pragma unroll
      for (int j = 0; j < 4; ++j)
        acc[i][j] = __builtin_amdgcn_mfma_f32_16x16x32_bf16(a[i], b[j], acc[i][j], 0, 0, 0);
    __syncthreads();
  }
#pragma unroll
  for (int i = 0; i < 4; ++i)
#pragma unroll
    for (int j = 0; j < 4; ++j)
#pragma unroll
      for (int r = 0; r < 4; ++r) {
        size_t row = rowA0 + wr * 64 + i * 16 + lg * 4 + r;
        size_t col = colB0 + wc * 64 + j * 16 + lr;
        if constexpr (sizeof(CT) == 2) C[row * N + col] = (CT)bf16_rne(acc[i][j][r]);
        else C[row * N + col] = acc[i][j][r];
      }
}

// ---------------- flash attention (dbuf, 1 barrier/iter, packed P) ----------------
// QKV [4096][3072]: Q at col h*128, K at 2048+kv*128. Vt [512][4096] = V^T (t-interleaved).
// K LDS: [32 t][128 d], 256B rows, byte XOR (t&7)<<4.
// V LDS: [32 r][128], row r holds d=4r..4r+3 (64B runs, t-interleaved), byte XOR (r&7)<<4.
// P LDS: u32[32 q][20], word c packs bf16 pair (t=2c-interleave) -> b128 A-frag reads.
template <int NSPLIT>
__global__ __launch_bounds__(256, 3) void attn_kernel(const short* __restrict__ QKV,
                                                      const short* __restrict__ Vt,
                                                      short* __restrict__ Oat,
                                                      _Float16* __restrict__ Op,
                                                      float* __restrict__ ml) {
  __shared__ __align__(16) short Ks[2][32 * 128];
  __shared__ __align__(16) short Vs[2][32 * 128];
  __shared__ __align__(16) u32 Ps[4][32 * 20];  // per-wave packed P, stride 20 words
  int tid = threadIdx.x, wave = tid >> 6, lane = tid & 63;
  int lr = lane & 15, lg = lane >> 4;
  int h = blockIdx.y, kv = h >> 2;
  int part = (NSPLIT == 2) ? blockIdx.z : 0;
  int q0 = blockIdx.x * 128 + wave * 32;

  short8 qf[2][4];
#pragma unroll
  for (int rt = 0; rt < 2; ++rt)
#pragma unroll
    for (int ks = 0; ks < 4; ++ks)
      qf[rt][ks] = *(const short8*)&QKV[(size_t)(q0 + rt * 16 + lr) * 3072 + h * 128 +
                                        ks * 32 + lg * 8];

  f32x4 oacc[2][8] = {};
  float m_run[2][4], lsum[2][4];
#pragma unroll
  for (int rt = 0; rt < 2; ++rt)
#pragma unroll
    for (int r = 0; r < 4; ++r) { m_run[rt][r] = -1e30f; lsum[rt][r] = 0.f; }

  const float sc = 1.44269504089f * 0.08838834764831845f;  // log2e / sqrt(128)
  const float THR_S = 60.f;                                 // defer-max threshold (S units)
  const short* Kbase = QKV + 2048 + kv * 128;
  const short* Vbase = Vt + (size_t)(kv * 128) * SEQ;

  auto stageK = [&](int b, int t0) {
#pragma unroll
    for (int c = 0; c < 2; ++c) {
      int chunk = wave * 2 + c;
      int row = chunk * 4 + lg;
      int colb = (lr * 16) ^ ((row & 7) << 4);
      gload16(Kbase + (size_t)(t0 + row) * 3072 + colb / 2, &Ks[b][chunk * 512]);
    }
  };
  auto stageV = [&](int b, int t0) {
#pragma unroll
    for (int c = 0; c < 2; ++c) {
      int chunk = wave * 2 + c;
      int r = chunk * 4 + lg;
      int lb = (lr * 16) ^ ((r & 7) << 4);
      int d = r * 4 + (lb >> 6);
      gload16(Vbase + (size_t)d * SEQ + t0 + ((lb & 63) >> 1), &Vs[b][chunk * 512]);
    }
  };

  const int tbeg = part * (SEQ / NSPLIT);
  const int tend = tbeg + SEQ / NSPLIT;

  stageK(0, tbeg);
  stageV(0, tbeg);
  __syncthreads();
  int buf = 0;

  for (int t0 = tbeg; t0 < tend; t0 += 32) {
    int tn = (t0 + 32 < tend) ? t0 + 32 : tbeg;  // clamped: last iter reloads harmlessly
    stageK(buf ^ 1, tn);
    stageV(buf ^ 1, tn);

    // S = Q K^T from Ks[buf]
    f32x4 sacc[2][2] = {};
    __builtin_amdgcn_s_setprio(1);
#pragma unroll
    for (int ks = 0; ks < 4; ++ks) {
      short8 kf[2];
#pragma unroll
      for (int ct = 0; ct < 2; ++ct) {
        int trow = ct * 16 + lr;
        int cb = (ks * 64 + lg * 16) ^ ((trow & 7) << 4);
        kf[ct] = *(const short8*)&Ks[buf][trow * 128 + cb / 2];
      }
#pragma unroll
      for (int rt = 0; rt < 2; ++rt)
#pragma unroll
        for (int ct = 0; ct < 2; ++ct)
          sacc[rt][ct] =
              __builtin_amdgcn_mfma_f32_16x16x32_bf16(qf[rt][ks], kf[ct], sacc[rt][ct], 0, 0, 0);
    }
    __builtin_amdgcn_s_setprio(0);

    // defer-max: shuffle-free local check; full reduce+rescale only when fired
    float vmax[2][4];
    int need = 0;
#pragma unroll
    for (int rt = 0; rt < 2; ++rt)
#pragma unroll
      for (int r = 0; r < 4; ++r) {
        vmax[rt][r] = fmaxf(sacc[rt][0][r], sacc[rt][1][r]);
        need |= (vmax[rt][r] > m_run[rt][r] + THR_S) ? 1 : 0;
      }
    if (__any(need)) {
#pragma unroll
      for (int rt = 0; rt < 2; ++rt)
#pragma unroll
        for (int r = 0; r < 4; ++r) {
          float v = vmax[rt][r];
          v = fmaxf(v, __shfl_xor(v, 1));
          v = fmaxf(v, __shfl_xor(v, 2));
          v = fmaxf(v, __shfl_xor(v, 4));
          v = fmaxf(v, __shfl_xor(v, 8));
          float mnew = fmaxf(m_run[rt][r], v);
          float corr = __builtin_amdgcn_exp2f((m_run[rt][r] - mnew) * sc);
          lsum[rt][r] *= corr;
          m_run[rt][r] = mnew;
#pragma unroll
          for (int db = 0; db < 8; ++db) oacc[rt][db][r] *= corr;
        }
    }
#pragma unroll
    for (int rt = 0; rt < 2; ++rt)
#pragma unroll
      for (int r = 0; r < 4; ++r) {
        float p0 = __builtin_amdgcn_exp2f((sacc[rt][0][r] - m_run[rt][r]) * sc);
        float p1 = __builtin_amdgcn_exp2f((sacc[rt][1][r] - m_run[rt][r]) * sc);
        lsum[rt][r] += p0 + p1;
        u32 pk;
        asm("v_cvt_pk_bf16_f32 %0, %1, %2" : "=v"(pk) : "v"(p0), "v"(p1));
        Ps[wave][(rt * 16 + lg * 4 + r) * 20 + lr] = pk;  // (t=lr, t=lr+16) pair
      }
    // Ps is wave-private: no barrier needed, compiler orders via lgkmcnt.

    // PV: O += P[32q x 32t] * V[32t x 128d] from Vs[buf] (t-interleaved on both sides)
    short8 pa[2];
#pragma unroll
    for (int rt = 0; rt < 2; ++rt)
      pa[rt] = *(const short8*)&Ps[wave][(rt * 16 + lr) * 20 + lg * 4];
    __builtin_amdgcn_s_setprio(1);
#pragma unroll
    for (int db = 0; db < 8; ++db) {
      int d = db * 16 + lr;
      int r = d >> 2;
      int lb = ((d & 3) * 64 + lg * 16) ^ ((r & 7) << 4);
      short8 bv = *(const short8*)&Vs[buf][r * 128 + lb / 2];
#pragma unroll
      for (int rt = 0; rt < 2; ++rt)
        oacc[rt][db] = __builtin_amdgcn_mfma_f32_16x16x32_bf16(pa[rt], bv, oacc[rt][db], 0, 0, 0);
    }
    __builtin_amdgcn_s_setprio(0);

    __syncthreads();  // next buffer staged; all waves done reading buf
    buf ^= 1;
  }

  // final cross-lane reduce of per-lane partial l
#pragma unroll
  for (int rt = 0; rt < 2; ++rt)
#pragma unroll
    for (int r = 0; r < 4; ++r) {
      float s = lsum[rt][r];
      s += __shfl_xor(s, 1);
      s += __shfl_xor(s, 2);
      s += __shfl_xor(s, 4);
      s += __shfl_xor(s, 8);
      lsum[rt][r] = s;
    }

  if constexpr (NSPLIT == 1) {
#pragma unroll
    for (int rt = 0; rt < 2; ++rt)
#pragma unroll
      for (int db = 0; db < 8; ++db)
#pragma unroll
        for (int r = 0; r < 4; ++r) {
          size_t row = q0 + rt * 16 + lg * 4 + r;
          size_t col = h * 128 + db * 16 + lr;
          Oat[row * HID + col] = bf16_rne(oacc[rt][db][r] / lsum[rt][r]);
        }
  } else {
    _Float16* Obase = Op + (size_t)part * SEQ * HID;
#pragma unroll
    for (int rt = 0; rt < 2; ++rt)
#pragma unroll
      for (int db = 0; db < 8; ++db)
#pragma unroll
        for (int r = 0; r < 4; ++r) {
          size_t row = q0 + rt * 16 + lg * 4 + r;
          size_t col = h * 128 + db * 16 + lr;
          Obase[row * HID + col] = (_Float16)oacc[rt][db][r];
        }
    if (lr == 0) {
#pragma unroll
      for (int rt = 0; rt < 2; ++rt)
#pragma unroll
        for (int r = 0; r < 4; ++r) {
          size_t row = q0 + rt * 16 + lg * 4 + r;
          size_t base = (((size_t)part * SEQ + row) * 16 + h) * 2;
          ml[base] = m_run[rt][r];
          ml[base + 1] = lsum[rt][r];
        }
    }
  }
}

// ---------------- merge two KV partitions ----------------
__global__ __launch_bounds__(256) void merge_parts(const _Float16* __restrict__ Op,
                                                   const float* __restrict__ ml,
                                                   short* __restrict__ Oat) {
  const float sc = 1.44269504089f * 0.08838834764831845f;
  int i = blockIdx.x * 256 + threadIdx.x;
  int row = i >> 8;
  int col = (i & 255) * 8;
  int h = col >> 7;
  const float* a = ml + (((size_t)row) * 16 + h) * 2;
  const float* b = ml + (((size_t)SEQ + row) * 16 + h) * 2;
  float m1 = a[0], l1 = a[1], m2 = b[0], l2 = b[1];
  float M = fmaxf(m1, m2);
  float e1 = __builtin_amdgcn_exp2f((m1 - M) * sc);
  float e2 = __builtin_amdgcn_exp2f((m2 - M) * sc);
  float inv = 1.f / (l1 * e1 + l2 * e2);
  half8 o1 = *(const half8*)&Op[(size_t)row * HID + col];
  half8 o2 = *(const half8*)&Op[(size_t)SEQ * HID + (size_t)row * HID + col];
  short8 o;
#pragma unroll
  for (int j = 0; j < 8; ++j)
    o[j] = bf16_rne(((float)o1[j] * e1 + (float)o2[j] * e2) * inv);
  *(short8*)&Oat[(size_t)row * HID + col] = o;
}

extern "C" void kernel_launch(void* const* d_in, const int* in_sizes, int n_in,
                              void* d_out, int out_size, void* d_ws, size_t ws_size,
                              hipStream_t stream) {
  const float* x = (const float*)d_in[0];
  const float* Wq = (const float*)d_in[1];
  const float* Wk = (const float*)d_in[2];
  const float* Wv = (const float*)d_in[3];
  const float* Wo = (const float*)d_in[4];
  float* out = (float*)d_out;
  char* ws = (char*)d_ws;

  // workspace layout:
  short* xb = (short*)(ws);                          // [4096][2048]  16MB (later: Oat)
  short* wqkv = (short*)(ws + (16u << 20));          // [3072][2048]  12MB (later: Vt)
  short* wob = (short*)(ws + (28u << 20));           // [2048][2048]   8MB
  short* qkv = (short*)(ws + (36u << 20));           // [4096][3072]  24MB
  short* vt = wqkv;                                  // [512][4096]    4MB
  short* oat = xb;                                   // [4096][2048]  16MB
  _Float16* opart = (_Float16*)(ws + 62914560u);     // [2][4096][2048] fp16 32MB
  float* mlb = (float*)(ws + 62914560u + 33554432u); // [2][4096][16][2] 1MB
  const bool split = ws_size >= (size_t)(62914560u + 33554432u + 1048576u);

  cast_bf16<<<4096, 256, 0, stream>>>(x, xb, 1048576);
  cast_bf16<<<2048, 256, 0, stream>>>(Wq, wqkv, 524288);
  cast_bf16<<<512, 256, 0, stream>>>(Wk, wqkv + (size_t)2048 * 2048, 131072);
  cast_bf16<<<512, 256, 0, stream>>>(Wv, wqkv + (size_t)2560 * 2048, 131072);
  cast_bf16<<<2048, 256, 0, stream>>>(Wo, wob, 524288);

  // QKV = x * [Wq;Wk;Wv]^T : [4096][3072]
  gemm_nt<short><<<dim3(24, 32), 256, 0, stream>>>(xb, wqkv, qkv, 4096, 3072, 2048);
  // V^T (t-interleaved) for the PV step
  transpose_v<<<dim3(64, 8), 256, 0, stream>>>(qkv, vt);
  // fused flash attention
  if (split) {
    attn_kernel<2><<<dim3(32, 16, 2), 256, 0, stream>>>(qkv, vt, nullptr, opart, mlb);
    merge_parts<<<4096, 256, 0, stream>>>(opart, mlb, oat);
  } else {
    attn_kernel<1><<<dim3(32, 16, 1), 256, 0, stream>>>(qkv, vt, oat, nullptr, nullptr);
  }
  // out = Oat * Wo^T (fp32 out)
  gemm_nt<float><<<dim3(16, 32), 256, 0, stream>>>(oat, wob, out, 4096, HID, 2048);
}